// Round 2
// baseline (679.026 us; speedup 1.0000x reference)
//
#include <hip/hip_runtime.h>
#include <stdint.h>

#define BATCH 4096
#define NEXP 64

typedef __bf16 bf16x8 __attribute__((ext_vector_type(8)));
typedef float f32x4 __attribute__((ext_vector_type(4)));
typedef unsigned int u32x4 __attribute__((ext_vector_type(4)));
typedef unsigned short u16x4 __attribute__((ext_vector_type(4)));
typedef unsigned short u16x8 __attribute__((ext_vector_type(8)));

__device__ __forceinline__ unsigned short f2bf(float f) {
  unsigned u = __builtin_bit_cast(unsigned, f);
  u += 0x7fffu + ((u >> 16) & 1u);
  return (unsigned short)(u >> 16);
}
__device__ __forceinline__ float bf2f(unsigned short h) {
  unsigned u = ((unsigned)h) << 16;
  return __builtin_bit_cast(float, u);
}

// async global->LDS, 16B per lane. LDS dest = wave-uniform base + lane*16.
__device__ __forceinline__ void async_copy16(const void* g, void* l) {
  __builtin_amdgcn_global_load_lds(
      (const __attribute__((address_space(1))) void*)(uintptr_t)g,
      (__attribute__((address_space(3))) void*)(uintptr_t)l, 16, 0, 0);
}

enum { AM_PLAIN = 0, AM_BN = 1, AM_EXPERT = 2 };

// ---------------------------------------------------------------------------
// Generic MFMA GEMM: C_slice[b,n] = sum_k A(b,k) * PB(k,n)  (+ bias[n])
//   A built on the fly per AMODE. B (PB) is fragment-major packed bf16:
//   fragment (kt32, nsub16) is 512 contiguous bf16; element (lane,j) =
//   B[kt*32 + (lane>>4)*8 + j][nsub*16 + (lane&15)]  -- exactly the
//   mfma_f32_16x16x32_bf16 B-operand layout, so global->LDS->frag is a flat
//   copy + conflict-free ds_read_b128.
// ---------------------------------------------------------------------------
template <int BN_, int WR, int WC, int AMODE>
__global__ __launch_bounds__(256, 2) void gemm_k(
    const float* __restrict__ Af32, const float* __restrict__ scv,
    const float* __restrict__ shv, const float* __restrict__ alphaPtr,
    const unsigned short* __restrict__ zbf, const float* __restrict__ wmat,
    const float* __restrict__ invPtr, int shI, int EI,
    const unsigned short* __restrict__ PB, int K, int nsubsTot,
    float* __restrict__ Cbase, long partStride,
    const float* __restrict__ biasv, int N, int ktilesTot, int splits) {
  constexpr int BM = 128, BK = 64;
  constexpr int MS = BM / 16;   // A subtiles (8)
  constexpr int NS = BN_ / 16;  // B subtiles per block
  constexpr int WTM = BM / WR, WTN = BN_ / WC;
  constexpr int TM = WTM / 16, TN = WTN / 16;
  static_assert(BN_ == 64 || BN_ == 128, "");

  __shared__ __align__(16) unsigned short As[2 * MS * 512];
  __shared__ __align__(16) unsigned short Bs[2 * NS * 512];

  const int tid = threadIdx.x;
  const int lane = tid & 63;
  const int wid = tid >> 6;
  const int wrow = wid / WC, wcol = wid % WC;

  const int m0 = blockIdx.x * BM;
  const int ntile = blockIdx.y;
  const int n0 = ntile * BN_;
  const int slice = blockIdx.z;
  const int kt0 = (int)((long)slice * ktilesTot / splits);
  const int kt1 = (int)((long)(slice + 1) * ktilesTot / splits);

  float* __restrict__ Cp = Cbase + (long)slice * partStride;

  const int ac = tid & 7;   // which 8-wide k chunk within BK
  const int am = tid >> 3;  // row 0..31 (+32*p)

  float alpha = 0.f, inv = 0.f;
  if constexpr (AMODE == AM_BN) alpha = alphaPtr[0];
  if constexpr (AMODE == AM_EXPERT) inv = invPtr[0];

  f32x4 acc[TM][TN] = {};

  for (int kt = kt0; kt < kt1; ++kt) {
    const int k0 = kt * BK;

    // ---- stage B: 2*NS fragments of 1KB, one wave-instruction each
    for (int f = wid; f < 2 * NS; f += 4) {
      const int fkt = f / NS, fns = f % NS;
      const long fragIdx = (long)(k0 / 32 + fkt) * nsubsTot + (ntile * NS + fns);
      async_copy16(PB + fragIdx * 512 + lane * 8, &Bs[f * 512 + lane * 8]);
    }

    // ---- stage A: build bf16 fragment-packed tile
    const int kk = ac * 8;
    const int kg = k0 + kk;
#pragma unroll
    for (int p = 0; p < 4; ++p) {
      const int m = am + p * 32;
      const long mg = m0 + m;
      float vals[8];
      if constexpr (AMODE == AM_PLAIN) {
        const f32x4* src = (const f32x4*)(Af32 + mg * K + kg);
        f32x4 a0 = src[0], a1 = src[1];
#pragma unroll
        for (int j = 0; j < 4; ++j) { vals[j] = a0[j]; vals[4 + j] = a1[j]; }
      } else if constexpr (AMODE == AM_BN) {
        const f32x4* src = (const f32x4*)(Af32 + mg * K + kg);
        f32x4 a0 = src[0], a1 = src[1];
        f32x4 s0 = *(const f32x4*)(scv + kg), s1 = *(const f32x4*)(scv + kg + 4);
        f32x4 h0 = *(const f32x4*)(shv + kg), h1 = *(const f32x4*)(shv + kg + 4);
#pragma unroll
        for (int j = 0; j < 4; ++j) {
          float v = fmaf(a0[j], s0[j], h0[j]);
          vals[j] = v >= 0.f ? v : alpha * v;
          float v2 = fmaf(a1[j], s1[j], h1[j]);
          vals[4 + j] = v2 >= 0.f ? v2 : alpha * v2;
        }
      } else {  // AM_EXPERT
        if (kg >= EI) {  // folded-bias region: A = wn[b, kg-EI]
          const f32x4* wr_ = (const f32x4*)(wmat + mg * NEXP + (kg - EI));
          f32x4 w0 = wr_[0], w1 = wr_[1];
#pragma unroll
          for (int j = 0; j < 4; ++j) {
            vals[j] = w0[j] * inv;
            vals[4 + j] = w1[j] * inv;
          }
        } else {  // A = wn[b,e] * z[b,i]
          const int e = kg >> shI;
          const int i0 = kg & ((1 << shI) - 1);
          const float wv = wmat[mg * NEXP + e] * inv;
          u16x8 zz = *(const u16x8*)(zbf + (mg << shI) + i0);
#pragma unroll
          for (int j = 0; j < 8; ++j) vals[j] = wv * bf2f(zz[j]);
        }
      }
      u16x8 ob;
#pragma unroll
      for (int j = 0; j < 8; ++j) ob[j] = f2bf(vals[j]);
      *(u16x8*)&As[((ac >> 2) * MS + (m >> 4)) * 512 +
                   (((ac & 3) << 4) | (m & 15)) * 8] = ob;
    }
    __syncthreads();

    // ---- MFMA
#pragma unroll
    for (int ks = 0; ks < 2; ++ks) {
      bf16x8 af[TM], bfr[TN];
#pragma unroll
      for (int i = 0; i < TM; ++i) {
        const int msub = wrow * TM + i;
        af[i] = __builtin_bit_cast(
            bf16x8, *(const u32x4*)&As[(ks * MS + msub) * 512 + lane * 8]);
      }
#pragma unroll
      for (int j = 0; j < TN; ++j) {
        const int nsub = wcol * TN + j;
        bfr[j] = __builtin_bit_cast(
            bf16x8, *(const u32x4*)&Bs[(ks * NS + nsub) * 512 + lane * 8]);
      }
#pragma unroll
      for (int i = 0; i < TM; ++i)
#pragma unroll
        for (int j = 0; j < TN; ++j)
          acc[i][j] = __builtin_amdgcn_mfma_f32_16x16x32_bf16(af[i], bfr[j],
                                                              acc[i][j], 0, 0, 0);
    }
    __syncthreads();
  }

  // ---- epilogue: C/D layout col=lane&15, row=(lane>>4)*4+reg
  const int q = lane >> 4, nn = lane & 15;
#pragma unroll
  for (int i = 0; i < TM; ++i) {
    const int rowb = m0 + wrow * WTM + i * 16 + q * 4;
#pragma unroll
    for (int j = 0; j < TN; ++j) {
      const int col = n0 + wcol * WTN + j * 16 + nn;
      const float bv = biasv ? biasv[col] : 0.f;
#pragma unroll
      for (int r = 0; r < 4; ++r)
        Cp[(long)(rowb + r) * N + col] = acc[i][j][r] + bv;
    }
  }
}

// ---------------------------------------------------------------------------
// BN stats: one block per column; sums split-K partials, emits fused
// scale/shift: sc=g*rsqrt(var+eps), sh=b-mu*sc  (biased var, eps=1e-5)
// ---------------------------------------------------------------------------
__global__ void stats_k(const float* __restrict__ H, long partStride, int nparts,
                        int C, const float* __restrict__ g,
                        const float* __restrict__ b, float* __restrict__ scv,
                        float* __restrict__ shv) {
  const int c = blockIdx.x;
  float s = 0.f, s2 = 0.f;
  for (int r = threadIdx.x; r < BATCH; r += 256) {
    float x = 0.f;
    for (int p = 0; p < nparts; ++p) x += H[p * partStride + (long)r * C + c];
    s += x;
    s2 += x * x;
  }
  __shared__ float sb[256], qb[256];
  sb[threadIdx.x] = s;
  qb[threadIdx.x] = s2;
  __syncthreads();
  for (int st = 128; st > 0; st >>= 1) {
    if (threadIdx.x < st) {
      sb[threadIdx.x] += sb[threadIdx.x + st];
      qb[threadIdx.x] += qb[threadIdx.x + st];
    }
    __syncthreads();
  }
  if (threadIdx.x == 0) {
    float mu = sb[0] * (1.f / BATCH);
    float var = qb[0] * (1.f / BATCH) - mu * mu;
    float isig = 1.f / sqrtf(var + 1e-5f);
    float sc_ = g[c] * isig;
    scv[c] = sc_;
    shv[c] = b[c] - mu * sc_;
  }
}

// z = bf16(prelu(sc*sum(Hparts)+sh))
__global__ void zbuild_k(const float* __restrict__ H, long partStride, int nparts,
                         const float* __restrict__ scv,
                         const float* __restrict__ shv,
                         const float* __restrict__ alphaPtr,
                         unsigned short* __restrict__ z, int C, int total4) {
  const int idx = blockIdx.x * 256 + threadIdx.x;
  if (idx >= total4) return;
  const float alpha = alphaPtr[0];
  const int c0 = (idx * 4) & (C - 1);
  f32x4 x = {0.f, 0.f, 0.f, 0.f};
  for (int p = 0; p < nparts; ++p) x += *(const f32x4*)(H + p * partStride + (long)idx * 4);
  f32x4 sv = *(const f32x4*)(scv + c0);
  f32x4 hv = *(const f32x4*)(shv + c0);
  u16x4 o;
#pragma unroll
  for (int j = 0; j < 4; ++j) {
    float v = fmaf(x[j], sv[j], hv[j]);
    v = v >= 0.f ? v : alpha * v;
    o[j] = f2bf(v);
  }
  *(u16x4*)(z + (long)idx * 4) = o;
}

// w = prelu(bn(G3)) fp32, + global sum (for wn = w/w_sum)
__global__ void wbuild_k(const float* __restrict__ G, const float* __restrict__ scv,
                         const float* __restrict__ shv,
                         const float* __restrict__ alphaPtr,
                         float* __restrict__ w, float* __restrict__ wsum) {
  const int idx = blockIdx.x * 256 + threadIdx.x;  // exactly 65536 threads
  const float alpha = alphaPtr[0];
  const int c0 = (idx * 4) & 63;
  f32x4 x = *(const f32x4*)(G + (long)idx * 4);
  f32x4 sv = *(const f32x4*)(scv + c0);
  f32x4 hv = *(const f32x4*)(shv + c0);
  f32x4 o;
  float part = 0.f;
#pragma unroll
  for (int j = 0; j < 4; ++j) {
    float v = fmaf(x[j], sv[j], hv[j]);
    v = v >= 0.f ? v : alpha * v;
    o[j] = v;
    part += v;
  }
  *(f32x4*)(w + (long)idx * 4) = o;
  __shared__ float sb[256];
  sb[threadIdx.x] = part;
  __syncthreads();
  for (int st = 128; st > 0; st >>= 1) {
    if (threadIdx.x < st) sb[threadIdx.x] += sb[threadIdx.x + st];
    __syncthreads();
  }
  if (threadIdx.x == 0) atomicAdd(wsum, sb[0]);
}

__global__ void inv_k(const float* __restrict__ wsum, float* __restrict__ invp) {
  if (threadIdx.x == 0 && blockIdx.x == 0) invp[0] = 1.0f / wsum[0];
}

__global__ void cast_k(const float* __restrict__ x, unsigned short* __restrict__ z,
                       int total4) {
  const int idx = blockIdx.x * 256 + threadIdx.x;
  if (idx >= total4) return;
  f32x4 v = *(const f32x4*)(x + (long)idx * 4);
  u16x4 o;
#pragma unroll
  for (int j = 0; j < 4; ++j) o[j] = f2bf(v[j]);
  *(u16x4*)(z + (long)idx * 4) = o;
}

// W[e,o,i] fp32 (+bias[e,o] folded as K rows EI..EI+E) -> fragment-major bf16
__global__ void prepack_k(const float* __restrict__ W, const float* __restrict__ bias,
                          unsigned short* __restrict__ PB, int O, int shI, int EI,
                          long totalChunks) {
  const long t = (long)blockIdx.x * 256 + threadIdx.x;
  if (t >= totalChunks) return;
  const int lane = (int)(t & 63);
  const long frag = t >> 6;
  const int nsubs = O / 16;
  const int nsub = (int)(frag % nsubs);
  const long ktile = frag / nsubs;
  const int n = nsub * 16 + (lane & 15);
  const int k = (int)(ktile * 32 + (lane >> 4) * 8);
  u16x8 o;
  if (k < EI) {
    const int e = k >> shI;
    const int i0 = k & ((1 << shI) - 1);
    const float* src = W + ((long)e * O + n) * (1 << shI) + i0;
    f32x4 a0 = *(const f32x4*)src;
    f32x4 a1 = *(const f32x4*)(src + 4);
#pragma unroll
    for (int j = 0; j < 4; ++j) {
      o[j] = f2bf(a0[j]);
      o[4 + j] = f2bf(a1[j]);
    }
  } else {
#pragma unroll
    for (int j = 0; j < 8; ++j) {
      const int ee = k + j - EI;
      o[j] = f2bf(bias[(long)ee * O + n]);
    }
  }
  *(u16x8*)(PB + t * 8) = o;
}

__global__ void reduce8_k(const float* __restrict__ P, long partStride,
                          float* __restrict__ out, int total4) {
  const int idx = blockIdx.x * 256 + threadIdx.x;
  if (idx >= total4) return;
  f32x4 s = {0.f, 0.f, 0.f, 0.f};
#pragma unroll
  for (int p = 0; p < 8; ++p) s += *(const f32x4*)(P + p * partStride + (long)idx * 4);
  *(f32x4*)(out + (long)idx * 4) = s;
}

// ---------------------------------------------------------------------------
extern "C" void kernel_launch(void* const* d_in, const int* in_sizes, int n_in,
                              void* d_out, int out_size, void* d_ws, size_t ws_size,
                              hipStream_t stream) {
  const float* m0 = (const float*)d_in[0];
  const float* x0 = (const float*)d_in[1];
  const float* mW1 = (const float*)d_in[2];
  const float* mb1 = (const float*)d_in[3];
  const float* mg1 = (const float*)d_in[4];
  const float* mbe1 = (const float*)d_in[5];
  const float* ma1 = (const float*)d_in[6];
  const float* mW2 = (const float*)d_in[7];
  const float* mb2 = (const float*)d_in[8];
  const float* mg2 = (const float*)d_in[9];
  const float* mbe2 = (const float*)d_in[10];
  const float* ma2 = (const float*)d_in[11];
  const float* mW3 = (const float*)d_in[12];
  const float* mb3 = (const float*)d_in[13];
  const float* mg3 = (const float*)d_in[14];
  const float* mbe3 = (const float*)d_in[15];
  const float* ma3 = (const float*)d_in[16];
  const float* Wenc0 = (const float*)d_in[17];
  const float* benc0 = (const float*)d_in[18];
  const float* Wenc1 = (const float*)d_in[19];
  const float* benc1 = (const float*)d_in[20];
  const float* Wdec0 = (const float*)d_in[21];
  const float* bdec0 = (const float*)d_in[22];
  const float* Wdec1 = (const float*)d_in[23];
  const float* bdec1 = (const float*)d_in[24];
  const float* bng = (const float*)d_in[25];
  const float* bnb = (const float*)d_in[26];
  const float* aexp = (const float*)d_in[27];

  char* base = (char*)d_ws;
  size_t off = 0;
  auto alloc = [&](size_t bytes) {
    void* p = base + off;
    off = (off + bytes + 255) & ~(size_t)255;
    return p;
  };
  unsigned short* PB = (unsigned short*)alloc(16448L * 256 * 2);  // 8.4 MB, reused per layer
  float* P0 = (float*)alloc(BATCH * 256 * 4);  // split-K partials / MNet activations
  float* P1 = (float*)alloc(BATCH * 256 * 4);
  float* P2 = (float*)alloc(BATCH * 256 * 4);
  float* P3 = (float*)alloc(BATCH * 256 * 4);
  (void)P2; (void)P3;
  unsigned short* zA = (unsigned short*)alloc(BATCH * 256 * 2);
  unsigned short* zB = (unsigned short*)alloc(BATCH * 256 * 2);
  unsigned short* zx0 = (unsigned short*)alloc(BATCH * 64 * 2);
  float* wbuf = (float*)alloc(BATCH * 64 * 4);
  float* scv = (float*)alloc(256 * 4);
  float* shv = (float*)alloc(256 * 4);
  float* wsum = (float*)alloc(256);
  float* invp = (float*)alloc(256);

  const dim3 blk(256);
  const long PS = BATCH * 256;  // partial stride (elements) for split-K=4 layers

  // ---- MNet L1: G1 = m0 @ mW1^T + mb1  -> P0 [4096,256]
  prepack_k<<<16, blk, 0, stream>>>(mW1, nullptr, PB, 256, 7, 128, 4096);
  gemm_k<128, 2, 2, AM_PLAIN><<<dim3(32, 2, 1), blk, 0, stream>>>(
      m0, nullptr, nullptr, nullptr, nullptr, nullptr, nullptr, 0, 0, PB, 128, 16,
      P0, 0, mb1, 256, 2, 1);
  stats_k<<<256, blk, 0, stream>>>(P0, 0, 1, 256, mg1, mbe1, scv, shv);

  // ---- MNet L2: G2 = prelu(bn(G1)) @ mW2^T + mb2 -> P1 [4096,128]
  prepack_k<<<16, blk, 0, stream>>>(mW2, nullptr, PB, 128, 8, 256, 4096);
  gemm_k<128, 2, 2, AM_BN><<<dim3(32, 1, 1), blk, 0, stream>>>(
      P0, scv, shv, ma1, nullptr, nullptr, nullptr, 0, 0, PB, 256, 8, P1, 0, mb2,
      128, 4, 1);
  stats_k<<<128, blk, 0, stream>>>(P1, 0, 1, 128, mg2, mbe2, scv, shv);

  // ---- MNet L3: G3 = prelu(bn(G2)) @ mW3^T + mb3 -> P0 [4096,64]
  prepack_k<<<4, blk, 0, stream>>>(mW3, nullptr, PB, 64, 7, 128, 1024);
  gemm_k<64, 4, 1, AM_BN><<<dim3(32, 1, 1), blk, 0, stream>>>(
      P1, scv, shv, ma2, nullptr, nullptr, nullptr, 0, 0, PB, 128, 4, P0, 0, mb3,
      64, 2, 1);
  stats_k<<<64, blk, 0, stream>>>(P0, 0, 1, 64, mg3, mbe3, scv, shv);

  // ---- w = prelu(bn(G3)); w_sum; inv; x0 -> bf16
  hipMemsetAsync(wsum, 0, 4, stream);
  wbuild_k<<<256, blk, 0, stream>>>(P0, scv, shv, ma3, wbuf, wsum);
  inv_k<<<1, 64, 0, stream>>>(wsum, invp);
  cast_k<<<256, blk, 0, stream>>>(x0, zx0, 65536);

  // ---- enc0: K=64*64+64=4160, split-K=4 -> P0..P3
  prepack_k<<<520, blk, 0, stream>>>(Wenc0, benc0, PB, 256, 6, 4096, 133120);
  gemm_k<128, 2, 2, AM_EXPERT><<<dim3(32, 2, 4), blk, 0, stream>>>(
      nullptr, nullptr, nullptr, nullptr, zx0, wbuf, invp, 6, 4096, PB, 4160, 16,
      P0, PS, nullptr, 256, 65, 4);
  stats_k<<<256, blk, 0, stream>>>(P0, PS, 4, 256, bng, bnb, scv, shv);
  zbuild_k<<<1024, blk, 0, stream>>>(P0, PS, 4, scv, shv, aexp, zA, 256, 262144);

  // ---- enc1: K=64*256+64=16448, split-K=4
  prepack_k<<<2056, blk, 0, stream>>>(Wenc1, benc1, PB, 256, 8, 16384, 526336);
  gemm_k<128, 2, 2, AM_EXPERT><<<dim3(32, 2, 4), blk, 0, stream>>>(
      nullptr, nullptr, nullptr, nullptr, zA, wbuf, invp, 8, 16384, PB, 16448, 16,
      P0, PS, nullptr, 256, 257, 4);
  stats_k<<<256, blk, 0, stream>>>(P0, PS, 4, 256, bng, bnb, scv, shv);
  zbuild_k<<<1024, blk, 0, stream>>>(P0, PS, 4, scv, shv, aexp, zB, 256, 262144);

  // ---- dec0
  prepack_k<<<2056, blk, 0, stream>>>(Wdec0, bdec0, PB, 256, 8, 16384, 526336);
  gemm_k<128, 2, 2, AM_EXPERT><<<dim3(32, 2, 4), blk, 0, stream>>>(
      nullptr, nullptr, nullptr, nullptr, zB, wbuf, invp, 8, 16384, PB, 16448, 16,
      P0, PS, nullptr, 256, 257, 4);
  stats_k<<<256, blk, 0, stream>>>(P0, PS, 4, 256, bng, bnb, scv, shv);
  zbuild_k<<<1024, blk, 0, stream>>>(P0, PS, 4, scv, shv, aexp, zA, 256, 262144);

  // ---- dec1: N=64, split-K=8 -> 8 partials of [4096,64] overlaid on P-region
  prepack_k<<<514, blk, 0, stream>>>(Wdec1, bdec1, PB, 64, 8, 16384, 131584);
  gemm_k<64, 4, 1, AM_EXPERT><<<dim3(32, 1, 8), blk, 0, stream>>>(
      nullptr, nullptr, nullptr, nullptr, zA, wbuf, invp, 8, 16384, PB, 16448, 4,
      P0, (long)BATCH * 64, nullptr, 64, 257, 8);
  // FIX (round 1 post-mortem): out has 262144 elems -> 65536 float4 chunks,
  // grid must be 256 blocks (was 64/16384: only 1/4 of d_out written).
  reduce8_k<<<256, blk, 0, stream>>>(P0, (long)BATCH * 64, (float*)d_out, 65536);

  (void)in_sizes; (void)n_in; (void)out_size; (void)ws_size;
}